// Round 9
// baseline (196.180 us; speedup 1.0000x reference)
//
#include <hip/hip_runtime.h>

// HOG (64,1,512,512) f32, skimage-compatible: orientations=9, cell=8, block=2x2, L2-Hys.
// K1: one 512-thr block per (image, 8-row strip x 512 cols). The 10-row halo strip
//     (20 KB) is staged into LDS via global_load_lds DMA (zero VGPR cost -> whole
//     block's fetch in flight at once; round-8 diagnosis: ~1 cache line/wave MLP).
//     Compute is column-per-thread (lane-consecutive LDS reads, conflict-free).
//     Binning math bit-identical to passing rounds (ocml atan2f + true /20.0f).
// K2: 2x2 sliding-block L2-Hys -> d_out (unchanged).

#define ORIENT 9
#define IMH 512
#define IMW 512
#define NCR 64
#define NCC 64
#define NBR 63
#define NBC 63
#define NIMG 64

#if defined(__has_builtin)
#if __has_builtin(__builtin_amdgcn_sqrtf)
#define FAST_SQRT(x) __builtin_amdgcn_sqrtf(x)
#else
#define FAST_SQRT(x) sqrtf(x)
#endif
#else
#define FAST_SQRT(x) sqrtf(x)
#endif

// ---------------------------------------------------------------------------
// Kernel 1. grid (64 strips, 64 images), block 512 (8 waves).
// LDS rows t=0..9 hold global rows rA-1 .. rA+8 (OOB rows zero-filled).
// Thread c (0..511) computes pixels (rA..rA+7, c), accumulating into cell c>>3.
// ---------------------------------------------------------------------------
__global__ __launch_bounds__(512) void hog_cell_hist(const float* __restrict__ img,
                                                     float* __restrict__ hist) {
    __shared__ float lds[10 * IMW];             // 20 KB image strip
    __shared__ float lh[NCC * ORIENT];          // 576 floats: 64 cell hists
    const int tid  = threadIdx.x;               // 0..511
    const int lane = tid & 63;
    const int wv   = tid >> 6;                  // wave id 0..7
    const int strip = blockIdx.x;               // 0..63 (cell row)
    const int b     = blockIdx.y;               // image
    const int rA    = strip * 8;
    const float* im = img + (size_t)b * (IMH * IMW);

    lh[tid % 576] = 0.f;                        // tid<512 covers [0,512)
    if (tid < 64) lh[512 + tid] = 0.f;

    // ---- DMA stage: 20 chunks (10 rows x 2 halves of 1KB), spread over 8 waves.
    // LDS dest = wave-uniform base (+ lane*16 added by HW); global src per-lane.
    for (int k = wv; k < 20; k += 8) {
        const int t = k >> 1, h = k & 1;
        const int g = rA - 1 + t;               // global row
        float* ldst = &lds[t * IMW + h * 256];  // wave-uniform
        if ((unsigned)g < IMH) {
            const float* gsrc = im + ((size_t)g * IMW + h * 256 + lane * 4);
            __builtin_amdgcn_global_load_lds(
                (const __attribute__((address_space(1))) void*)gsrc,
                (__attribute__((address_space(3))) void*)ldst, 16, 0, 0);
        } else {
            float4 z = {0.f, 0.f, 0.f, 0.f};
            *(float4*)(ldst + lane * 4) = z;    // zero halo row (value unused: gr predicated)
        }
    }
    __syncthreads();                            // drains vmcnt(0) + lgkmcnt(0)

    // ---- compute: column c, 8 pixels vertically. Lane-consecutive LDS reads.
    const int c = tid;
    float col[10];
#pragma unroll
    for (int t = 0; t < 10; ++t) col[t] = lds[t * IMW + c];
    const int cl = (c > 0)       ? c - 1 : 0;   // index safe; value predicated out at c==0
    const int cr = (c < IMW - 1) ? c + 1 : IMW - 1;
    float lf[8], rg[8];
#pragma unroll
    for (int t = 0; t < 8; ++t) { lf[t] = lds[(t + 1) * IMW + cl]; rg[t] = lds[(t + 1) * IMW + cr]; }

    const bool cin = (c > 0) && (c < IMW - 1);
    float mags[8]; int bins[8];
#pragma unroll
    for (int t = 0; t < 8; ++t) {
        const int r = rA + t;
        const bool rin = (r > 0) && (r < IMH - 1);
        const float gr = rin ? (col[t + 2] - col[t]) : 0.f;   // img[r+1]-img[r-1]
        const float gc = cin ? (rg[t] - lf[t])       : 0.f;   // img[c+1]-img[c-1]
        mags[t] = FAST_SQRT(gr * gr + gc * gc);
        // degrees(atan2) floor-mod 180 — bit-identical to all passing rounds
        // (incl. ori==180 -> bin 0 for the gr==+0, gc<0 border case).
        float ori = atan2f(gr, gc) * 57.29577951308232f;
        ori = (ori >= 180.0f) ? ori - 180.0f : ori;
        ori = (ori <   0.0f) ? ori + 180.0f : ori;
        int bin = (int)(ori / 20.0f);            // true division: matches XLA
        bins[t] = bin > (ORIENT - 1) ? (ORIENT - 1) : bin;
    }
    float* cellh = &lh[(c >> 3) * ORIENT];
#pragma unroll
    for (int t = 0; t < 8; ++t) atomicAdd(&cellh[bins[t]], mags[t]);
    __syncthreads();

    // ---- writeback: 576 contiguous floats = hist[b][strip][0..63][0..8]
    float* hrow = hist + (((size_t)b * NCR + strip) * NCC) * ORIENT;
    hrow[tid] = lh[tid] * (1.f / 64.f);
    if (tid < 64) hrow[512 + tid] = lh[512 + tid] * (1.f / 64.f);
}

// ---------------------------------------------------------------------------
// Kernel 2 (unchanged): one 64-thread block per (image, block-row).
// ---------------------------------------------------------------------------
__global__ __launch_bounds__(64) void hog_block_norm(const float* __restrict__ hist,
                                                     float* __restrict__ out) {
    __shared__ float lh[2 * NCC * ORIENT];      // 1152 floats
    const int tid = threadIdx.x;                // 0..63
    const int br  = blockIdx.x;                 // 0..62
    const int b   = blockIdx.y;                 // 0..63

    const float4* src = (const float4*)(hist + ((size_t)b * NCR + br) * (NCC * ORIENT));
    float4* dst = (float4*)lh;
#pragma unroll
    for (int k = 0; k < 5; ++k) {               // 288 float4 / 64 threads
        int idx = k * 64 + tid;
        if (idx < 288) dst[idx] = src[idx];
    }
    __syncthreads();

    const int bc = tid;
    if (bc >= NBC) return;

    float v[36];
    float s = 0.f;
#pragma unroll
    for (int k = 0; k < 18; ++k) { float h = lh[bc * ORIENT + k];                v[k]      = h; s += h * h; }
#pragma unroll
    for (int k = 0; k < 18; ++k) { float h = lh[NCC * ORIENT + bc * ORIENT + k]; v[18 + k] = h; s += h * h; }

    const float r1 = 1.0f / sqrtf(s + 1e-10f);  // EPS^2
    float s2 = 0.f;
#pragma unroll
    for (int k = 0; k < 36; ++k) {
        float x = fminf(v[k] * r1, 0.2f);
        v[k] = x;
        s2 += x * x;
    }
    const float r2 = 1.0f / sqrtf(s2 + 1e-10f);

    float4* o = (float4*)(out + (((size_t)b * NBR + br) * NBC + bc) * 36);
#pragma unroll
    for (int k = 0; k < 9; ++k)
        o[k] = make_float4(v[4*k] * r2, v[4*k+1] * r2, v[4*k+2] * r2, v[4*k+3] * r2);
}

// ---------------------------------------------------------------------------
extern "C" void kernel_launch(void* const* d_in, const int* in_sizes, int n_in,
                              void* d_out, int out_size, void* d_ws, size_t ws_size,
                              hipStream_t stream) {
    const float* x = (const float*)d_in[0];
    float* out  = (float*)d_out;
    float* hist = (float*)d_ws;                 // 64*64*64*9 f32 = 9.44 MB

    dim3 b1(512, 1, 1);
    dim3 g1(NCR, NIMG, 1);                      // (64 strips, 64 images)
    hipLaunchKernelGGL(hog_cell_hist, g1, b1, 0, stream, x, hist);

    dim3 b2(64, 1, 1);
    dim3 g2(NBR, NIMG, 1);                      // (63, 64)
    hipLaunchKernelGGL(hog_block_norm, g2, b2, 0, stream, hist, out);
}

// Round 10
// 196.092 us; speedup vs baseline: 1.0005x; 1.0005x over previous
//
#include <hip/hip_runtime.h>

// HOG (64,1,512,512) f32, skimage-compatible: orientations=9, cell=8, block=2x2, L2-Hys.
// K1: one 512-thr block per (image, 8-row strip). Strip staged to LDS via
//     global_load_lds DMA (r9). NEW: pixel loop is ROLLED (~100-inst body, I$-resident)
//     to test/fix the instruction-fetch-bound diagnosis (VALUBusy fell 39->26% as
//     unroll grew across rounds while duration stayed ~100us).
//     Binning math bit-identical to all passing rounds (ocml atan2f + true /20.0f).
// K2: 2x2 sliding-block L2-Hys -> d_out (unchanged).

#define ORIENT 9
#define IMH 512
#define IMW 512
#define NCR 64
#define NCC 64
#define NBR 63
#define NBC 63
#define NIMG 64

// ---------------------------------------------------------------------------
// Kernel 1. grid (64 strips, 64 images), block 512 (8 waves).
// LDS rows t=0..9 hold global rows rA-1 .. rA+8 (OOB rows zero-filled).
// Thread c computes pixels (rA..rA+7, c) in a rolled loop reading LDS directly.
// ---------------------------------------------------------------------------
__global__ __launch_bounds__(512) void hog_cell_hist(const float* __restrict__ img,
                                                     float* __restrict__ hist) {
    __shared__ float lds[10 * IMW];             // 20 KB image strip
    __shared__ float lh[NCC * ORIENT];          // 576 floats: 64 cell hists
    const int tid  = threadIdx.x;               // 0..511
    const int lane = tid & 63;
    const int wv   = tid >> 6;                  // wave id 0..7
    const int strip = blockIdx.x;               // 0..63 (cell row)
    const int b     = blockIdx.y;               // image
    const int rA    = strip * 8;
    const float* im = img + (size_t)b * (IMH * IMW);

    lh[tid % 576] = 0.f;                        // covers [0,512)
    if (tid < 64) lh[512 + tid] = 0.f;

    // ---- DMA stage: 20 chunks (10 rows x 2 halves of 1KB), spread over 8 waves.
    for (int k = wv; k < 20; k += 8) {
        const int t = k >> 1, h = k & 1;
        const int g = rA - 1 + t;               // global row
        float* ldst = &lds[t * IMW + h * 256];  // wave-uniform dest
        if ((unsigned)g < IMH) {
            const float* gsrc = im + ((size_t)g * IMW + h * 256 + lane * 4);
            __builtin_amdgcn_global_load_lds(
                (const __attribute__((address_space(1))) void*)gsrc,
                (__attribute__((address_space(3))) void*)ldst, 16, 0, 0);
        } else {
            float4 z = {0.f, 0.f, 0.f, 0.f};
            *(float4*)(ldst + lane * 4) = z;    // zero halo row (value predicated out)
        }
    }
    __syncthreads();                            // drains vmcnt(0) + lgkmcnt(0)

    // ---- compute: column c, 8 pixels vertically. ROLLED loop, tiny I$ footprint.
    const int c = tid;
    const bool cin = (c > 0) && (c < IMW - 1);
    const int cl = cin ? c - 1 : c;
    const int cr = cin ? c + 1 : c;
    float* cellh = &lh[(c >> 3) * ORIENT];

#pragma clang loop unroll(disable)
    for (int t = 0; t < 8; ++t) {
        const int r = rA + t;
        const float up = lds[t * IMW + c];          // row r-1
        const float dn = lds[(t + 2) * IMW + c];    // row r+1
        const float lf = lds[(t + 1) * IMW + cl];   // row r, col c-1
        const float rg = lds[(t + 1) * IMW + cr];   // row r, col c+1
        const bool rin = (r > 0) && (r < IMH - 1);
        const float gr = rin ? (dn - up) : 0.f;
        const float gc = cin ? (rg - lf) : 0.f;
        const float mag = sqrtf(gr * gr + gc * gc);
        // degrees(atan2) floor-mod 180 — bit-identical to all passing rounds
        // (incl. ori==180 -> bin 0 for the gr==+0, gc<0 border case).
        float ori = atan2f(gr, gc) * 57.29577951308232f;
        ori = (ori >= 180.0f) ? ori - 180.0f : ori;
        ori = (ori <   0.0f) ? ori + 180.0f : ori;
        int bin = (int)(ori / 20.0f);               // true division: matches XLA
        bin = bin > (ORIENT - 1) ? (ORIENT - 1) : bin;
        atomicAdd(&cellh[bin], mag);
    }
    __syncthreads();

    // ---- writeback: 576 contiguous floats = hist[b][strip][0..63][0..8]
    float* hrow = hist + (((size_t)b * NCR + strip) * NCC) * ORIENT;
    hrow[tid] = lh[tid] * (1.f / 64.f);
    if (tid < 64) hrow[512 + tid] = lh[512 + tid] * (1.f / 64.f);
}

// ---------------------------------------------------------------------------
// Kernel 2 (unchanged): one 64-thread block per (image, block-row).
// ---------------------------------------------------------------------------
__global__ __launch_bounds__(64) void hog_block_norm(const float* __restrict__ hist,
                                                     float* __restrict__ out) {
    __shared__ float lh[2 * NCC * ORIENT];      // 1152 floats
    const int tid = threadIdx.x;                // 0..63
    const int br  = blockIdx.x;                 // 0..62
    const int b   = blockIdx.y;                 // 0..63

    const float4* src = (const float4*)(hist + ((size_t)b * NCR + br) * (NCC * ORIENT));
    float4* dst = (float4*)lh;
#pragma unroll
    for (int k = 0; k < 5; ++k) {               // 288 float4 / 64 threads
        int idx = k * 64 + tid;
        if (idx < 288) dst[idx] = src[idx];
    }
    __syncthreads();

    const int bc = tid;
    if (bc >= NBC) return;

    float v[36];
    float s = 0.f;
#pragma unroll
    for (int k = 0; k < 18; ++k) { float h = lh[bc * ORIENT + k];                v[k]      = h; s += h * h; }
#pragma unroll
    for (int k = 0; k < 18; ++k) { float h = lh[NCC * ORIENT + bc * ORIENT + k]; v[18 + k] = h; s += h * h; }

    const float r1 = 1.0f / sqrtf(s + 1e-10f);  // EPS^2
    float s2 = 0.f;
#pragma unroll
    for (int k = 0; k < 36; ++k) {
        float x = fminf(v[k] * r1, 0.2f);
        v[k] = x;
        s2 += x * x;
    }
    const float r2 = 1.0f / sqrtf(s2 + 1e-10f);

    float4* o = (float4*)(out + (((size_t)b * NBR + br) * NBC + bc) * 36);
#pragma unroll
    for (int k = 0; k < 9; ++k)
        o[k] = make_float4(v[4*k] * r2, v[4*k+1] * r2, v[4*k+2] * r2, v[4*k+3] * r2);
}

// ---------------------------------------------------------------------------
extern "C" void kernel_launch(void* const* d_in, const int* in_sizes, int n_in,
                              void* d_out, int out_size, void* d_ws, size_t ws_size,
                              hipStream_t stream) {
    const float* x = (const float*)d_in[0];
    float* out  = (float*)d_out;
    float* hist = (float*)d_ws;                 // 64*64*64*9 f32 = 9.44 MB

    dim3 b1(512, 1, 1);
    dim3 g1(NCR, NIMG, 1);                      // (64 strips, 64 images)
    hipLaunchKernelGGL(hog_cell_hist, g1, b1, 0, stream, x, hist);

    dim3 b2(64, 1, 1);
    dim3 g2(NBR, NIMG, 1);                      // (63, 64)
    hipLaunchKernelGGL(hog_block_norm, g2, b2, 0, stream, hist, out);
}

// Round 11
// 195.749 us; speedup vs baseline: 1.0022x; 1.0017x over previous
//
#include <hip/hip_runtime.h>

// HOG (64,1,512,512) f32, skimage-compatible: orientations=9, cell=8, block=2x2, L2-Hys.
// K1: r10 structure (LDS-DMA strip, rolled pixel loop). NEW: comparison-based
//     sector binning (8 cross-product signs, ~50 VALU/px vs ~175 for the ocml
//     atan2f chain). Pixels within 1e-4 of a boundary fall back to the exact
//     atan2f chain of the 5x-passing kernels -> decisions unchanged everywhere.
// K2: 2x2 sliding-block L2-Hys -> d_out (unchanged).

#define ORIENT 9
#define IMH 512
#define IMW 512
#define NCR 64
#define NCC 64
#define NBR 63
#define NBC 63
#define NIMG 64

// ---------------------------------------------------------------------------
// Kernel 1. grid (64 strips, 64 images), block 512 (8 waves).
// LDS rows t=0..9 hold global rows rA-1 .. rA+8 (OOB rows zero-filled).
// ---------------------------------------------------------------------------
__global__ __launch_bounds__(512) void hog_cell_hist(const float* __restrict__ img,
                                                     float* __restrict__ hist) {
    __shared__ float lds[10 * IMW];             // 20 KB image strip
    __shared__ float lh[NCC * ORIENT];          // 576 floats: 64 cell hists
    const int tid  = threadIdx.x;               // 0..511
    const int lane = tid & 63;
    const int wv   = tid >> 6;                  // wave id 0..7
    const int strip = blockIdx.x;               // 0..63 (cell row)
    const int b     = blockIdx.y;               // image
    const int rA    = strip * 8;
    const float* im = img + (size_t)b * (IMH * IMW);

    lh[tid] = 0.f;
    if (tid < 64) lh[512 + tid] = 0.f;

    // ---- DMA stage: 20 chunks (10 rows x 2 halves of 1KB), spread over 8 waves.
    for (int k = wv; k < 20; k += 8) {
        const int t = k >> 1, h = k & 1;
        const int g = rA - 1 + t;               // global row
        float* ldst = &lds[t * IMW + h * 256];  // wave-uniform dest
        if ((unsigned)g < IMH) {
            const float* gsrc = im + ((size_t)g * IMW + h * 256 + lane * 4);
            __builtin_amdgcn_global_load_lds(
                (const __attribute__((address_space(1))) void*)gsrc,
                (__attribute__((address_space(3))) void*)ldst, 16, 0, 0);
        } else {
            float4 z = {0.f, 0.f, 0.f, 0.f};
            *(float4*)(ldst + lane * 4) = z;    // zero halo row (value predicated out)
        }
    }
    __syncthreads();                            // drains vmcnt(0) + lgkmcnt(0)

    // cos/sin of bin boundaries 20..160 deg (f32-rounded exact values)
    const float BC[8] = { 0.93969262f,  0.76604444f,  0.50f,  0.17364818f,
                         -0.17364818f, -0.50f, -0.76604444f, -0.93969262f };
    const float BS[8] = { 0.34202014f,  0.64278761f,  0.86602540f, 0.98480775f,
                          0.98480775f,  0.86602540f,  0.64278761f, 0.34202014f };

    // ---- compute: column c, 8 pixels vertically. Rolled loop.
    const int c = tid;
    const bool cin = (c > 0) && (c < IMW - 1);
    const int cl = cin ? c - 1 : c;
    const int cr = cin ? c + 1 : c;
    float* cellh = &lh[(c >> 3) * ORIENT];

#pragma clang loop unroll(disable)
    for (int t = 0; t < 8; ++t) {
        const int r = rA + t;
        const float up = lds[t * IMW + c];          // row r-1
        const float dn = lds[(t + 2) * IMW + c];    // row r+1
        const float lf = lds[(t + 1) * IMW + cl];   // row r, col c-1
        const float rg = lds[(t + 1) * IMW + cr];   // row r, col c+1
        const bool rin = (r > 0) && (r < IMH - 1);
        const float gr = rin ? (dn - up) : 0.f;     // y
        const float gc = cin ? (rg - lf) : 0.f;     // x
        const float mag = sqrtf(gr * gr + gc * gc);

        // Fast bin: normalize direction to upper half-plane (flip iff the
        // first nonzero of (y, x) is negative — reproduces ori==180 -> bin 0),
        // then count boundaries passed via cross-product signs.
        const float sel = (gr == 0.0f) ? gc : gr;
        const bool flip = (sel < 0.0f);
        const float yp = flip ? -gr : gr;
        const float xp = flip ? -gc : gc;
        int bin = 0;
        float minc = 1e30f;
#pragma unroll
        for (int k = 0; k < 8; ++k) {
            const float cross = yp * BC[k] - xp * BS[k];
            bin += (cross >= 0.0f) ? 1 : 0;
            minc = fminf(minc, fabsf(cross));
        }
        // Boundary band (~0.008 deg): defer to the exact chain used by all
        // previous passing rounds, so every borderline decision is unchanged.
        if (minc < 1e-4f * (fabsf(gc) + fabsf(gr))) {
            float ori = atan2f(gr, gc) * 57.29577951308232f;
            ori = (ori >= 180.0f) ? ori - 180.0f : ori;
            ori = (ori <   0.0f) ? ori + 180.0f : ori;
            int sb = (int)(ori / 20.0f);            // true division: matches XLA
            bin = sb > (ORIENT - 1) ? (ORIENT - 1) : sb;
        }
        atomicAdd(&cellh[bin], mag);
    }
    __syncthreads();

    // ---- writeback: 576 contiguous floats = hist[b][strip][0..63][0..8]
    float* hrow = hist + (((size_t)b * NCR + strip) * NCC) * ORIENT;
    hrow[tid] = lh[tid] * (1.f / 64.f);
    if (tid < 64) hrow[512 + tid] = lh[512 + tid] * (1.f / 64.f);
}

// ---------------------------------------------------------------------------
// Kernel 2 (unchanged): one 64-thread block per (image, block-row).
// ---------------------------------------------------------------------------
__global__ __launch_bounds__(64) void hog_block_norm(const float* __restrict__ hist,
                                                     float* __restrict__ out) {
    __shared__ float lh[2 * NCC * ORIENT];      // 1152 floats
    const int tid = threadIdx.x;                // 0..63
    const int br  = blockIdx.x;                 // 0..62
    const int b   = blockIdx.y;                 // 0..63

    const float4* src = (const float4*)(hist + ((size_t)b * NCR + br) * (NCC * ORIENT));
    float4* dst = (float4*)lh;
#pragma unroll
    for (int k = 0; k < 5; ++k) {               // 288 float4 / 64 threads
        int idx = k * 64 + tid;
        if (idx < 288) dst[idx] = src[idx];
    }
    __syncthreads();

    const int bc = tid;
    if (bc >= NBC) return;

    float v[36];
    float s = 0.f;
#pragma unroll
    for (int k = 0; k < 18; ++k) { float h = lh[bc * ORIENT + k];                v[k]      = h; s += h * h; }
#pragma unroll
    for (int k = 0; k < 18; ++k) { float h = lh[NCC * ORIENT + bc * ORIENT + k]; v[18 + k] = h; s += h * h; }

    const float r1 = 1.0f / sqrtf(s + 1e-10f);  // EPS^2
    float s2 = 0.f;
#pragma unroll
    for (int k = 0; k < 36; ++k) {
        float x = fminf(v[k] * r1, 0.2f);
        v[k] = x;
        s2 += x * x;
    }
    const float r2 = 1.0f / sqrtf(s2 + 1e-10f);

    float4* o = (float4*)(out + (((size_t)b * NBR + br) * NBC + bc) * 36);
#pragma unroll
    for (int k = 0; k < 9; ++k)
        o[k] = make_float4(v[4*k] * r2, v[4*k+1] * r2, v[4*k+2] * r2, v[4*k+3] * r2);
}

// ---------------------------------------------------------------------------
extern "C" void kernel_launch(void* const* d_in, const int* in_sizes, int n_in,
                              void* d_out, int out_size, void* d_ws, size_t ws_size,
                              hipStream_t stream) {
    const float* x = (const float*)d_in[0];
    float* out  = (float*)d_out;
    float* hist = (float*)d_ws;                 // 64*64*64*9 f32 = 9.44 MB

    dim3 b1(512, 1, 1);
    dim3 g1(NCR, NIMG, 1);                      // (64 strips, 64 images)
    hipLaunchKernelGGL(hog_cell_hist, g1, b1, 0, stream, x, hist);

    dim3 b2(64, 1, 1);
    dim3 g2(NBR, NIMG, 1);                      // (63, 64)
    hipLaunchKernelGGL(hog_block_norm, g2, b2, 0, stream, hist, out);
}